// Round 3
// baseline (268.268 us; speedup 1.0000x reference)
//
#include <hip/hip_runtime.h>
#include <hip/hip_bf16.h>
#include <stdint.h>

#define EPS 1e-5f
#define LAMBDA 0.15f
#define START_ITERS 8000
#define ALLOWED_DELTA 200

typedef __attribute__((ext_vector_type(4))) float f32x4;
typedef __attribute__((ext_vector_type(8))) short bf16x8;

__device__ __forceinline__ ushort f2bf(float f) {
  union { float f; uint32_t u; } v = {f};
  uint32_t u = v.u;
  return (ushort)((u + 0x7FFF + ((u >> 16) & 1)) >> 16);  // RNE
}
__device__ __forceinline__ float bf2f(ushort b) {
  union { uint32_t u; float f; } v; v.u = ((uint32_t)b) << 16; return v.f;
}

// async global->LDS, 16B per lane; LDS dest must be wave-uniform base (lane scatter = lane*16)
__device__ __forceinline__ void gload16(const void* g, void* l) {
  __builtin_amdgcn_global_load_lds(
      (const __attribute__((address_space(1))) void*)(uintptr_t)(g),
      (__attribute__((address_space(3))) void*)(uint32_t)(uintptr_t)(l),
      16, 0, 0);
}

// ---------------- kernel 1: nx[r][k] = bf16( x[r][k] / max(||x[r,:]||, eps) ) ----------------
__global__ __launch_bounds__(256) void k_rownorm(const float* __restrict__ x,
                                                 ushort* __restrict__ nx) {
  const int K = 4096;
  int r = blockIdx.x, t = threadIdx.x;
  const f32x4* xr = (const f32x4*)(x + (size_t)r * K);
  f32x4 v[4];
  float s = 0.f;
#pragma unroll
  for (int p = 0; p < 4; ++p) {
    v[p] = xr[p * 256 + t];
    s += v[p].x * v[p].x + v[p].y * v[p].y + v[p].z * v[p].z + v[p].w * v[p].w;
  }
#pragma unroll
  for (int m = 1; m < 64; m <<= 1) s += __shfl_xor(s, m);
  __shared__ float red[4];
  if ((t & 63) == 0) red[t >> 6] = s;
  __syncthreads();
  float inv = 1.f / fmaxf(sqrtf(red[0] + red[1] + red[2] + red[3]), EPS);
#pragma unroll
  for (int p = 0; p < 4; ++p) {
    ushort4 o;
    o.x = f2bf(v[p].x * inv); o.y = f2bf(v[p].y * inv);
    o.z = f2bf(v[p].z * inv); o.w = f2bf(v[p].w * inv);
    *(ushort4*)(nx + (size_t)r * K + (size_t)(p * 256 + t) * 4) = o;
  }
}

// ---------------- kernel 2: wsumsq[c] = sum_a w[a][c]^2 (atomic partials) ----------------
__global__ __launch_bounds__(256) void k_wsumsq(const float* __restrict__ w,
                                                float* __restrict__ wsumsq) {
  const int N = 4096;
  int t = threadIdx.x;
  int c = blockIdx.x * 1024 + t * 4;
  int a0 = blockIdx.y * 64;
  f32x4 acc = {0.f, 0.f, 0.f, 0.f};
  for (int a = a0; a < a0 + 64; ++a) {
    f32x4 v = *(const f32x4*)(w + (size_t)a * N + c);
    acc += v * v;
  }
  atomicAdd(&wsumsq[c + 0], acc.x);
  atomicAdd(&wsumsq[c + 1], acc.y);
  atomicAdd(&wsumsq[c + 2], acc.z);
  atomicAdd(&wsumsq[c + 3], acc.w);
}

// ---------------- kernel 3: ql[a], winv[c] ----------------
__global__ __launch_bounds__(256) void k_prep(const int* __restrict__ qiters,
                                              const int* __restrict__ iters,
                                              const float* __restrict__ wsumsq,
                                              float* __restrict__ ql,
                                              float* __restrict__ winv) {
  int i = blockIdx.x * 256 + threadIdx.x;
  int it = iters[0] + 1;
  bool act = (it - qiters[i]) <= ALLOWED_DELTA;
  ql[i] = (it > START_ITERS && act) ? LAMBDA : 0.f;
  winv[i] = 1.f / fmaxf(sqrtf(wsumsq[i]), EPS);
}

// ---------------- kernel 4: injT[c][a] = bf16( w[a][c]*winv[c]*(1-ql[a]) + qf[c][a]*ql[a] )
//                  + injss[c] += sum_a injT[c][a]^2  (from bf16-rounded values) ----------------
__global__ __launch_bounds__(256) void k_combine(const float* __restrict__ w,
                                                 const float* __restrict__ qf,
                                                 const float* __restrict__ ql,
                                                 const float* __restrict__ winv,
                                                 ushort* __restrict__ injT,
                                                 float* __restrict__ injss) {
  const int N = 4096;
  __shared__ float wt[64][65];
  __shared__ float qls[64];
  __shared__ float wis[64];
  int a0 = blockIdx.y * 64, c0 = blockIdx.x * 64;
  int t = threadIdx.x;
  if (t < 64) qls[t] = ql[a0 + t];
  else if (t < 128) wis[t - 64] = winv[c0 + (t - 64)];
  int rr = t >> 4, cc = (t & 15) * 4;
#pragma unroll
  for (int p = 0; p < 4; ++p) {
    int ar = p * 16 + rr;
    f32x4 v = *(const f32x4*)(w + (size_t)(a0 + ar) * N + c0 + cc);
    wt[ar][cc + 0] = v.x; wt[ar][cc + 1] = v.y;
    wt[ar][cc + 2] = v.z; wt[ar][cc + 3] = v.w;
  }
  __syncthreads();
  int al = (t & 15) * 4;
#pragma unroll
  for (int p = 0; p < 4; ++p) {
    int c = p * 16 + rr;
    f32x4 q4 = *(const f32x4*)(qf + (size_t)(c0 + c) * N + a0 + al);
    float wi = wis[c];
    float ss = 0.f;
    ushort4 ob;
#pragma unroll
    for (int j = 0; j < 4; ++j) {
      float qla = qls[al + j];
      float val = wt[al + j][c] * wi * (1.f - qla) + q4[j] * qla;
      ushort b = f2bf(val);
      float vb = bf2f(b);
      ss += vb * vb;
      ((ushort*)&ob)[j] = b;
    }
    *(ushort4*)(injT + (size_t)(c0 + c) * N + a0 + al) = ob;
    ss += __shfl_xor(ss, 1); ss += __shfl_xor(ss, 2);
    ss += __shfl_xor(ss, 4); ss += __shfl_xor(ss, 8);
    if ((t & 15) == 0) atomicAdd(&injss[c0 + c], ss);
  }
}

// ---------------- kernel 5: scale[c] = 1/max(sqrt(injss[c]), eps) ----------------
__global__ __launch_bounds__(256) void k_scale(const float* __restrict__ injss,
                                               float* __restrict__ scale) {
  int i = blockIdx.x * 256 + threadIdx.x;
  scale[i] = 1.f / fmaxf(sqrtf(injss[i]), EPS);
}

// ---------------- kernel 6: C[r][c] = scale[c] * sum_k nx[r][k]*injT[c][k] ----------------
// A = nx [M=512][K=4096] bf16, B = injT [N=4096][K=4096] bf16 (B^T layout)
// BM=64 BN=128 BK=32, 256 thr (4 waves 2x2), wave = 32x64 out (2x4 MFMA 16x16x32)
__global__ __launch_bounds__(256) void k_gemm(const ushort* __restrict__ A,
                                              const ushort* __restrict__ B,
                                              const float* __restrict__ scale,
                                              float* __restrict__ C) {
  const int N = 4096, K = 4096, BK = 32;
  // LDS layout [kb][row][8]: element k = k0 + kb*8 + j  -> frag read = 1 ds_read_b128
  __shared__ __align__(16) ushort As[2][4][64][8];
  __shared__ __align__(16) ushort Bs[2][4][128][8];
  int tile_m = blockIdx.y * 64, tile_n = blockIdx.x * 128;
  int t = threadIdx.x;
  int lane = t & 63, wid = t >> 6;
  int wm = wid >> 1, wn = wid & 1;
  int kb = lane >> 4, fr = lane & 15;

  // staging source addresses (per-lane); LDS dests are wave-uniform
  const ushort* aSrc = A + (size_t)(tile_m + lane) * K + wid * 8;
  int bcol = (wid & 1) * 64 + lane;
  int bkb0 = wid >> 1;
  const ushort* bSrc = B + (size_t)(tile_n + bcol) * K + bkb0 * 8;

  f32x4 acc[2][4] = {};

  auto stage = [&](int buf, int k0) {
    gload16(aSrc + k0, &As[buf][wid][0][0]);
    gload16(bSrc + k0,      &Bs[buf][bkb0][(wid & 1) * 64][0]);
    gload16(bSrc + k0 + 16, &Bs[buf][2 + bkb0][(wid & 1) * 64][0]);
  };

  stage(0, 0);
  __syncthreads();  // drains vmcnt: buf0 ready
  const int NT = K / BK;  // 128
  for (int kt = 0; kt < NT; ++kt) {
    int cur = kt & 1;
    if (kt + 1 < NT) stage(cur ^ 1, (kt + 1) * BK);
    bf16x8 af[2], bfv[4];
#pragma unroll
    for (int m = 0; m < 2; ++m)
      af[m] = *(const bf16x8*)&As[cur][kb][wm * 32 + m * 16 + fr][0];
#pragma unroll
    for (int n = 0; n < 4; ++n)
      bfv[n] = *(const bf16x8*)&Bs[cur][kb][wn * 64 + n * 16 + fr][0];
#pragma unroll
    for (int m = 0; m < 2; ++m)
#pragma unroll
      for (int n = 0; n < 4; ++n)
        acc[m][n] = __builtin_amdgcn_mfma_f32_16x16x32_bf16(af[m], bfv[n], acc[m][n], 0, 0, 0);
    __syncthreads();  // compute done reading cur; next buf's loads drained
  }
  // epilogue: D mapping col=lane&15, row=(lane>>4)*4+reg  [m89-verified]
#pragma unroll
  for (int m = 0; m < 2; ++m) {
    int row0 = tile_m + wm * 32 + m * 16 + kb * 4;
#pragma unroll
    for (int n = 0; n < 4; ++n) {
      int col = tile_n + wn * 64 + n * 16 + fr;
      float sc = scale[col];
#pragma unroll
      for (int r = 0; r < 4; ++r)
        C[(size_t)(row0 + r) * N + col] = acc[m][n][r] * sc;
    }
  }
}

extern "C" void kernel_launch(void* const* d_in, const int* in_sizes, int n_in,
                              void* d_out, int out_size, void* d_ws, size_t ws_size,
                              hipStream_t stream) {
  const float* x   = (const float*)d_in[0];   // (512, 4096)
  const float* w   = (const float*)d_in[1];   // (4096, 4096)
  const float* qf  = (const float*)d_in[2];   // (4096, 4096)
  const int*   qit = (const int*)d_in[3];     // (4096,)
  const int*   its = (const int*)d_in[4];     // scalar
  float* out = (float*)d_out;                 // (512, 4096) fp32

  char* ws = (char*)d_ws;
  ushort* nx   = (ushort*)ws;                      // 4 MB bf16
  ushort* injT = (ushort*)(ws + (4u << 20));       // 32 MB bf16
  float* stats = (float*)(ws + (36u << 20));
  float* wsumsq = stats;          // 4096
  float* injss  = stats + 4096;   // 4096
  float* ql     = stats + 8192;
  float* winv   = stats + 12288;
  float* scale  = stats + 16384;

  hipMemsetAsync(stats, 0, 2 * 4096 * sizeof(float), stream);  // wsumsq + injss
  k_rownorm<<<512, 256, 0, stream>>>(x, nx);
  k_wsumsq<<<dim3(4, 64), 256, 0, stream>>>(w, wsumsq);
  k_prep<<<16, 256, 0, stream>>>(qit, its, wsumsq, ql, winv);
  k_combine<<<dim3(64, 64), 256, 0, stream>>>(w, qf, ql, winv, injT, injss);
  k_scale<<<16, 256, 0, stream>>>(injss, scale);
  k_gemm<<<dim3(32, 8), 256, 0, stream>>>(nx, injT, scale, out);
}

// Round 5
// 249.111 us; speedup vs baseline: 1.0769x; 1.0769x over previous
//
#include <hip/hip_runtime.h>
#include <hip/hip_bf16.h>
#include <stdint.h>

#define EPS 1e-5f
#define LAMBDA 0.15f
#define START_ITERS 8000
#define ALLOWED_DELTA 200

typedef __attribute__((ext_vector_type(4))) float f32x4;
typedef __attribute__((ext_vector_type(8))) short bf16x8;

__device__ __forceinline__ ushort f2bf(float f) {
  union { float f; uint32_t u; } v = {f};
  uint32_t u = v.u;
  return (ushort)((u + 0x7FFF + ((u >> 16) & 1)) >> 16);  // RNE
}
__device__ __forceinline__ float bf2f(ushort b) {
  union { uint32_t u; float f; } v; v.u = ((uint32_t)b) << 16; return v.f;
}

// async global->LDS, 16B per lane; LDS dest must be wave-uniform base (lane scatter = lane*16)
__device__ __forceinline__ void gload16(const void* g, void* l) {
  __builtin_amdgcn_global_load_lds(
      (const __attribute__((address_space(1))) void*)(uintptr_t)(g),
      (__attribute__((address_space(3))) void*)(uint32_t)(uintptr_t)(l),
      16, 0, 0);
}

// ---------------- kernel 1: nx[r][k] = bf16( x[r][k] / max(||x[r,:]||, eps) ) ----------------
__global__ __launch_bounds__(256) void k_rownorm(const float* __restrict__ x,
                                                 ushort* __restrict__ nx) {
  const int K = 4096;
  int r = blockIdx.x, t = threadIdx.x;
  const f32x4* xr = (const f32x4*)(x + (size_t)r * K);
  f32x4 v[4];
  float s = 0.f;
#pragma unroll
  for (int p = 0; p < 4; ++p) {
    v[p] = xr[p * 256 + t];
    s += v[p].x * v[p].x + v[p].y * v[p].y + v[p].z * v[p].z + v[p].w * v[p].w;
  }
#pragma unroll
  for (int m = 1; m < 64; m <<= 1) s += __shfl_xor(s, m);
  __shared__ float red[4];
  if ((t & 63) == 0) red[t >> 6] = s;
  __syncthreads();
  float inv = 1.f / fmaxf(sqrtf(red[0] + red[1] + red[2] + red[3]), EPS);
#pragma unroll
  for (int p = 0; p < 4; ++p) {
    ushort4 o;
    o.x = f2bf(v[p].x * inv); o.y = f2bf(v[p].y * inv);
    o.z = f2bf(v[p].z * inv); o.w = f2bf(v[p].w * inv);
    *(ushort4*)(nx + (size_t)r * K + (size_t)(p * 256 + t) * 4) = o;
  }
}

// ---------------- kernel 2: wsumsq[c] = sum_a w[a][c]^2 (atomic partials) ----------------
__global__ __launch_bounds__(256) void k_wsumsq(const float* __restrict__ w,
                                                float* __restrict__ wsumsq) {
  const int N = 4096;
  int t = threadIdx.x;
  int c = blockIdx.x * 1024 + t * 4;
  int a0 = blockIdx.y * 64;
  f32x4 acc = {0.f, 0.f, 0.f, 0.f};
  for (int a = a0; a < a0 + 64; ++a) {
    f32x4 v = *(const f32x4*)(w + (size_t)a * N + c);
    acc += v * v;
  }
  atomicAdd(&wsumsq[c + 0], acc.x);
  atomicAdd(&wsumsq[c + 1], acc.y);
  atomicAdd(&wsumsq[c + 2], acc.z);
  atomicAdd(&wsumsq[c + 3], acc.w);
}

// ---------------- kernel 3: ql[a], winv[c] ----------------
__global__ __launch_bounds__(256) void k_prep(const int* __restrict__ qiters,
                                              const int* __restrict__ iters,
                                              const float* __restrict__ wsumsq,
                                              float* __restrict__ ql,
                                              float* __restrict__ winv) {
  int i = blockIdx.x * 256 + threadIdx.x;
  int it = iters[0] + 1;
  bool act = (it - qiters[i]) <= ALLOWED_DELTA;
  ql[i] = (it > START_ITERS && act) ? LAMBDA : 0.f;
  winv[i] = 1.f / fmaxf(sqrtf(wsumsq[i]), EPS);
}

// ---------------- kernel 4: injT[c][a] = bf16( w[a][c]*winv[c]*(1-ql[a]) + qf[c][a]*ql[a] )
//                  + injss[c] += sum_a injT[c][a]^2  (from bf16-rounded values) ----------------
__global__ __launch_bounds__(256) void k_combine(const float* __restrict__ w,
                                                 const float* __restrict__ qf,
                                                 const float* __restrict__ ql,
                                                 const float* __restrict__ winv,
                                                 ushort* __restrict__ injT,
                                                 float* __restrict__ injss) {
  const int N = 4096;
  __shared__ float wt[64][65];
  __shared__ float qls[64];
  __shared__ float wis[64];
  int a0 = blockIdx.y * 64, c0 = blockIdx.x * 64;
  int t = threadIdx.x;
  if (t < 64) qls[t] = ql[a0 + t];
  else if (t < 128) wis[t - 64] = winv[c0 + (t - 64)];
  int rr = t >> 4, cc = (t & 15) * 4;
#pragma unroll
  for (int p = 0; p < 4; ++p) {
    int ar = p * 16 + rr;
    f32x4 v = *(const f32x4*)(w + (size_t)(a0 + ar) * N + c0 + cc);
    wt[ar][cc + 0] = v.x; wt[ar][cc + 1] = v.y;
    wt[ar][cc + 2] = v.z; wt[ar][cc + 3] = v.w;
  }
  __syncthreads();
  int al = (t & 15) * 4;
#pragma unroll
  for (int p = 0; p < 4; ++p) {
    int c = p * 16 + rr;
    f32x4 q4 = *(const f32x4*)(qf + (size_t)(c0 + c) * N + a0 + al);
    float wi = wis[c];
    float ss = 0.f;
    ushort4 ob;
#pragma unroll
    for (int j = 0; j < 4; ++j) {
      float qla = qls[al + j];
      float val = wt[al + j][c] * wi * (1.f - qla) + q4[j] * qla;
      ushort b = f2bf(val);
      float vb = bf2f(b);
      ss += vb * vb;
      ((ushort*)&ob)[j] = b;
    }
    *(ushort4*)(injT + (size_t)(c0 + c) * N + a0 + al) = ob;
    ss += __shfl_xor(ss, 1); ss += __shfl_xor(ss, 2);
    ss += __shfl_xor(ss, 4); ss += __shfl_xor(ss, 8);
    if ((t & 15) == 0) atomicAdd(&injss[c0 + c], ss);
  }
}

// ---------------- kernel 5: scale[c] = 1/max(sqrt(injss[c]), eps) ----------------
__global__ __launch_bounds__(256) void k_scale(const float* __restrict__ injss,
                                               float* __restrict__ scale) {
  int i = blockIdx.x * 256 + threadIdx.x;
  scale[i] = 1.f / fmaxf(sqrtf(injss[i]), EPS);
}

// ---------------- kernel 6: C[r][c] = scale[c] * sum_k nx[r][k]*injT[c][k] ----------------
// A = nx [M=512][K=4096] bf16, B = injT [N=4096][K=4096] bf16 (B^T layout)
// BM=64 BN=64 BK=64, 256 thr (4 waves 2x2), wave = 32x32 out (2x2 MFMA 16x16x32)
// grid 512 = 2 blocks/CU (LDS 32KB/block) -> 2 waves/SIMD for latency overlap
__global__ __launch_bounds__(256) void k_gemm(const ushort* __restrict__ A,
                                              const ushort* __restrict__ B,
                                              const float* __restrict__ scale,
                                              float* __restrict__ C) {
  const int N = 4096, K = 4096, BK = 64;
  // LDS layout [kb][row][8]: element k = k0 + kb*8 + j  -> frag read = 1 ds_read_b128
  __shared__ __align__(16) ushort As[2][8][64][8];
  __shared__ __align__(16) ushort Bs[2][8][64][8];
  int tile_m = blockIdx.y * 64, tile_n = blockIdx.x * 64;
  int t = threadIdx.x;
  int lane = t & 63, wid = t >> 6;
  int wm = wid >> 1, wn = wid & 1;
  int q = lane >> 4, fr = lane & 15;

  // staging: wave w covers kb {2w, 2w+1} for A and B; LDS dest wave-uniform, lane scatter = row
  const ushort* aSrc = A + (size_t)(tile_m + lane) * K + wid * 16;
  const ushort* bSrc = B + (size_t)(tile_n + lane) * K + wid * 16;

  f32x4 acc[2][2] = {};

  auto stage = [&](int buf, int k0) {
    gload16(aSrc + k0,     &As[buf][2 * wid][0][0]);
    gload16(aSrc + k0 + 8, &As[buf][2 * wid + 1][0][0]);
    gload16(bSrc + k0,     &Bs[buf][2 * wid][0][0]);
    gload16(bSrc + k0 + 8, &Bs[buf][2 * wid + 1][0][0]);
  };

  stage(0, 0);
  __syncthreads();  // drains vmcnt: buf0 ready
  const int NT = K / BK;  // 64
  for (int kt = 0; kt < NT; ++kt) {
    int cur = kt & 1;
    if (kt + 1 < NT) stage(cur ^ 1, (kt + 1) * BK);
#pragma unroll
    for (int kk = 0; kk < 2; ++kk) {
      int kbi = kk * 4 + q;
      bf16x8 af[2], bfv[2];
#pragma unroll
      for (int m = 0; m < 2; ++m)
        af[m] = *(const bf16x8*)&As[cur][kbi][wm * 32 + m * 16 + fr][0];
#pragma unroll
      for (int n = 0; n < 2; ++n)
        bfv[n] = *(const bf16x8*)&Bs[cur][kbi][wn * 32 + n * 16 + fr][0];
#pragma unroll
      for (int m = 0; m < 2; ++m)
#pragma unroll
        for (int n = 0; n < 2; ++n)
          acc[m][n] = __builtin_amdgcn_mfma_f32_16x16x32_bf16(af[m], bfv[n], acc[m][n], 0, 0, 0);
    }
    __syncthreads();  // compute done reading cur; next buf's loads drained
  }
  // epilogue: D mapping col=lane&15, row=(lane>>4)*4+reg  [m89-verified]
#pragma unroll
  for (int m = 0; m < 2; ++m) {
    int row0 = tile_m + wm * 32 + m * 16 + q * 4;
#pragma unroll
    for (int n = 0; n < 2; ++n) {
      int col = tile_n + wn * 32 + n * 16 + fr;
      float sc = scale[col];
#pragma unroll
      for (int r = 0; r < 4; ++r)
        C[(size_t)(row0 + r) * N + col] = acc[m][n][r] * sc;
    }
  }
}

extern "C" void kernel_launch(void* const* d_in, const int* in_sizes, int n_in,
                              void* d_out, int out_size, void* d_ws, size_t ws_size,
                              hipStream_t stream) {
  const float* x   = (const float*)d_in[0];   // (512, 4096)
  const float* w   = (const float*)d_in[1];   // (4096, 4096)
  const float* qf  = (const float*)d_in[2];   // (4096, 4096)
  const int*   qit = (const int*)d_in[3];     // (4096,)
  const int*   its = (const int*)d_in[4];     // scalar
  float* out = (float*)d_out;                 // (512, 4096) fp32

  char* ws = (char*)d_ws;
  ushort* nx   = (ushort*)ws;                      // 4 MB bf16
  ushort* injT = (ushort*)(ws + (4u << 20));       // 32 MB bf16
  float* stats = (float*)(ws + (36u << 20));
  float* wsumsq = stats;          // 4096
  float* injss  = stats + 4096;   // 4096
  float* ql     = stats + 8192;
  float* winv   = stats + 12288;
  float* scale  = stats + 16384;

  hipMemsetAsync(stats, 0, 2 * 4096 * sizeof(float), stream);  // wsumsq + injss
  k_rownorm<<<512, 256, 0, stream>>>(x, nx);
  k_wsumsq<<<dim3(4, 64), 256, 0, stream>>>(w, wsumsq);
  k_prep<<<16, 256, 0, stream>>>(qit, its, wsumsq, ql, winv);
  k_combine<<<dim3(64, 64), 256, 0, stream>>>(w, qf, ql, winv, injT, injss);
  k_scale<<<16, 256, 0, stream>>>(injss, scale);
  k_gemm<<<dim3(64, 8), 256, 0, stream>>>(nx, injT, scale, out);
}

// Round 7
// 242.663 us; speedup vs baseline: 1.1055x; 1.0266x over previous
//
#include <hip/hip_runtime.h>
#include <hip/hip_bf16.h>
#include <stdint.h>

#define EPS 1e-5f
#define LAMBDA 0.15f
#define START_ITERS 8000
#define ALLOWED_DELTA 200

typedef __attribute__((ext_vector_type(4))) float f32x4;
typedef __attribute__((ext_vector_type(8))) short bf16x8;

__device__ __forceinline__ ushort f2bf(float f) {
  union { float f; uint32_t u; } v = {f};
  uint32_t u = v.u;
  return (ushort)((u + 0x7FFF + ((u >> 16) & 1)) >> 16);  // RNE
}
__device__ __forceinline__ float bf2f(ushort b) {
  union { uint32_t u; float f; } v; v.u = ((uint32_t)b) << 16; return v.f;
}

// async global->LDS, 16B per lane; LDS dest must be wave-uniform base (lane scatter = lane*16)
__device__ __forceinline__ void gload16(const void* g, void* l) {
  __builtin_amdgcn_global_load_lds(
      (const __attribute__((address_space(1))) void*)(uintptr_t)(g),
      (__attribute__((address_space(3))) void*)(uint32_t)(uintptr_t)(l),
      16, 0, 0);
}

// ---------------- kernel 1: nx[r][k] = bf16( x[r][k] / max(||x[r,:]||, eps) ) ----------------
__global__ __launch_bounds__(256) void k_rownorm(const float* __restrict__ x,
                                                 ushort* __restrict__ nx) {
  const int K = 4096;
  int r = blockIdx.x, t = threadIdx.x;
  const f32x4* xr = (const f32x4*)(x + (size_t)r * K);
  f32x4 v[4];
  float s = 0.f;
#pragma unroll
  for (int p = 0; p < 4; ++p) {
    v[p] = xr[p * 256 + t];
    s += v[p].x * v[p].x + v[p].y * v[p].y + v[p].z * v[p].z + v[p].w * v[p].w;
  }
#pragma unroll
  for (int m = 1; m < 64; m <<= 1) s += __shfl_xor(s, m);
  __shared__ float red[4];
  if ((t & 63) == 0) red[t >> 6] = s;
  __syncthreads();
  float inv = 1.f / fmaxf(sqrtf(red[0] + red[1] + red[2] + red[3]), EPS);
#pragma unroll
  for (int p = 0; p < 4; ++p) {
    ushort4 o;
    o.x = f2bf(v[p].x * inv); o.y = f2bf(v[p].y * inv);
    o.z = f2bf(v[p].z * inv); o.w = f2bf(v[p].w * inv);
    *(ushort4*)(nx + (size_t)r * K + (size_t)(p * 256 + t) * 4) = o;
  }
}

// ---------------- kernel 2: wsumsq[c] = sum_a w[a][c]^2 (atomic partials) ----------------
__global__ __launch_bounds__(256) void k_wsumsq(const float* __restrict__ w,
                                                float* __restrict__ wsumsq) {
  const int N = 4096;
  int t = threadIdx.x;
  int c = blockIdx.x * 1024 + t * 4;
  int a0 = blockIdx.y * 64;
  f32x4 acc = {0.f, 0.f, 0.f, 0.f};
  for (int a = a0; a < a0 + 64; ++a) {
    f32x4 v = *(const f32x4*)(w + (size_t)a * N + c);
    acc += v * v;
  }
  atomicAdd(&wsumsq[c + 0], acc.x);
  atomicAdd(&wsumsq[c + 1], acc.y);
  atomicAdd(&wsumsq[c + 2], acc.z);
  atomicAdd(&wsumsq[c + 3], acc.w);
}

// ---------------- kernel 3: injT[c][a] = bf16( w[a][c]*winv[c]*(1-ql[a]) + qf[c][a]*ql[a] )
//                  + injss[c] += sum_a injT[c][a]^2  (bf16-rounded values)
//                  ql/winv computed inline (k_prep fused) ----------------
__global__ __launch_bounds__(256) void k_combine(const float* __restrict__ w,
                                                 const float* __restrict__ qf,
                                                 const int* __restrict__ qiters,
                                                 const int* __restrict__ iters,
                                                 const float* __restrict__ wsumsq,
                                                 ushort* __restrict__ injT,
                                                 float* __restrict__ injss) {
  const int N = 4096;
  __shared__ float wt[64][65];
  __shared__ float qls[64];
  __shared__ float wis[64];
  int a0 = blockIdx.y * 64, c0 = blockIdx.x * 64;
  int t = threadIdx.x;
  if (t < 64) {
    int it = iters[0] + 1;
    bool act = (it - qiters[a0 + t]) <= ALLOWED_DELTA;
    qls[t] = (it > START_ITERS && act) ? LAMBDA : 0.f;
  } else if (t < 128) {
    wis[t - 64] = 1.f / fmaxf(sqrtf(wsumsq[c0 + (t - 64)]), EPS);
  }
  int rr = t >> 4, cc = (t & 15) * 4;
#pragma unroll
  for (int p = 0; p < 4; ++p) {
    int ar = p * 16 + rr;
    f32x4 v = *(const f32x4*)(w + (size_t)(a0 + ar) * N + c0 + cc);
    wt[ar][cc + 0] = v.x; wt[ar][cc + 1] = v.y;
    wt[ar][cc + 2] = v.z; wt[ar][cc + 3] = v.w;
  }
  __syncthreads();
  int al = (t & 15) * 4;
#pragma unroll
  for (int p = 0; p < 4; ++p) {
    int c = p * 16 + rr;
    f32x4 q4 = *(const f32x4*)(qf + (size_t)(c0 + c) * N + a0 + al);
    float wi = wis[c];
    float ss = 0.f;
    ushort4 ob;
#pragma unroll
    for (int j = 0; j < 4; ++j) {
      float qla = qls[al + j];
      float val = wt[al + j][c] * wi * (1.f - qla) + q4[j] * qla;
      ushort b = f2bf(val);
      float vb = bf2f(b);
      ss += vb * vb;
      ((ushort*)&ob)[j] = b;
    }
    *(ushort4*)(injT + (size_t)(c0 + c) * N + a0 + al) = ob;
    ss += __shfl_xor(ss, 1); ss += __shfl_xor(ss, 2);
    ss += __shfl_xor(ss, 4); ss += __shfl_xor(ss, 8);
    if ((t & 15) == 0) atomicAdd(&injss[c0 + c], ss);
  }
}

// ---------------- kernel 4: C[r][c] = (1/max(sqrt(injss[c]),eps)) * sum_k nx[r][k]*injT[c][k]
// A = nx [512][4096] bf16, B = injT [4096][4096] bf16 (B^T layout)
// BM=64 BN=64 BK=64, 4 waves 2x2, wave = 32x32 out (2x2 MFMA 16x16x32)
// T3/T4: 3-buffer LDS, 2-deep prefetch, raw s_barrier + counted vmcnt(4)
// (never vmcnt(0) in steady state -> newest prefetch stays in flight across barrier)
__global__ __launch_bounds__(256) void k_gemm(const ushort* __restrict__ A,
                                              const ushort* __restrict__ B,
                                              const float* __restrict__ injss,
                                              float* __restrict__ C) {
  const int N = 4096, K = 4096, BK = 64;
  // LDS layout [buf][kb][row][8]: k = kt*64 + kb*8 + j -> frag read = 1 ds_read_b128
  __shared__ __align__(16) ushort As[3][8][64][8];
  __shared__ __align__(16) ushort Bs[3][8][64][8];
  int tile_m = blockIdx.y * 64, tile_n = blockIdx.x * 64;
  int t = threadIdx.x;
  int lane = t & 63, wid = t >> 6;
  int wm = wid >> 1, wn = wid & 1;
  int q = lane >> 4, fr = lane & 15;

  const ushort* aSrc = A + (size_t)(tile_m + lane) * K + wid * 16;
  const ushort* bSrc = B + (size_t)(tile_n + lane) * K + wid * 16;

  f32x4 acc[2][2] = {};

  auto stage = [&](int buf, int kt) {  // 4 gload_lds per wave
    int k0 = kt * BK;
    gload16(aSrc + k0,     &As[buf][2 * wid][0][0]);
    gload16(aSrc + k0 + 8, &As[buf][2 * wid + 1][0][0]);
    gload16(bSrc + k0,     &Bs[buf][2 * wid][0][0]);
    gload16(bSrc + k0 + 8, &Bs[buf][2 * wid + 1][0][0]);
  };
  auto compute = [&](int buf) {
#pragma unroll
    for (int kk = 0; kk < 2; ++kk) {
      int kbi = kk * 4 + q;
      bf16x8 af[2], bfv[2];
#pragma unroll
      for (int m = 0; m < 2; ++m)
        af[m] = *(const bf16x8*)&As[buf][kbi][wm * 32 + m * 16 + fr][0];
#pragma unroll
      for (int n = 0; n < 2; ++n)
        bfv[n] = *(const bf16x8*)&Bs[buf][kbi][wn * 32 + n * 16 + fr][0];
#pragma unroll
      for (int m = 0; m < 2; ++m)
#pragma unroll
        for (int n = 0; n < 2; ++n)
          acc[m][n] = __builtin_amdgcn_mfma_f32_16x16x32_bf16(af[m], bfv[n], acc[m][n], 0, 0, 0);
    }
  };

  const int NT = K / BK;  // 64
  // prologue: 2 tiles in flight (8 loads/wave)
  stage(0, 0);
  stage(1, 1);
  asm volatile("s_waitcnt vmcnt(4)" ::: "memory");  // buf0's 4 done; buf1's still flying
  __builtin_amdgcn_s_barrier();
  // steady state: one barrier per tile, newest prefetch never drained
  for (int kt = 0; kt < NT - 2; ++kt) {
    stage((kt + 2) % 3, kt + 2);
    compute(kt % 3);
    asm volatile("s_waitcnt vmcnt(4)" ::: "memory");  // buf[kt+1] ready; buf[kt+2] in flight
    __builtin_amdgcn_s_barrier();  // publishes buf[kt+1]; guards buf[kt] reuse at kt+1
  }
  // epilogue
  compute((NT - 2) % 3);
  asm volatile("s_waitcnt vmcnt(0)" ::: "memory");  // finish buf[NT-1]'s loads
  __builtin_amdgcn_s_barrier();
  compute((NT - 1) % 3);

  // epilogue: D mapping col=lane&15, row=(lane>>4)*4+reg  [m89-verified]; k_scale fused
#pragma unroll
  for (int m = 0; m < 2; ++m) {
    int row0 = tile_m + wm * 32 + m * 16 + q * 4;
#pragma unroll
    for (int n = 0; n < 2; ++n) {
      int col = tile_n + wn * 32 + n * 16 + fr;
      float sc = 1.f / fmaxf(sqrtf(injss[col]), EPS);
#pragma unroll
      for (int r = 0; r < 4; ++r)
        C[(size_t)(row0 + r) * N + col] = acc[m][n][r] * sc;
    }
  }
}

extern "C" void kernel_launch(void* const* d_in, const int* in_sizes, int n_in,
                              void* d_out, int out_size, void* d_ws, size_t ws_size,
                              hipStream_t stream) {
  const float* x   = (const float*)d_in[0];   // (512, 4096)
  const float* w   = (const float*)d_in[1];   // (4096, 4096)
  const float* qf  = (const float*)d_in[2];   // (4096, 4096)
  const int*   qit = (const int*)d_in[3];     // (4096,)
  const int*   its = (const int*)d_in[4];     // scalar
  float* out = (float*)d_out;                 // (512, 4096) fp32

  char* ws = (char*)d_ws;
  ushort* nx   = (ushort*)ws;                      // 4 MB bf16
  ushort* injT = (ushort*)(ws + (4u << 20));       // 32 MB bf16
  float* stats = (float*)(ws + (36u << 20));
  float* wsumsq = stats;          // 4096
  float* injss  = stats + 4096;   // 4096

  hipMemsetAsync(stats, 0, 2 * 4096 * sizeof(float), stream);  // wsumsq + injss
  k_rownorm<<<512, 256, 0, stream>>>(x, nx);
  k_wsumsq<<<dim3(4, 64), 256, 0, stream>>>(w, wsumsq);
  k_combine<<<dim3(64, 64), 256, 0, stream>>>(w, qf, qit, its, wsumsq, injT, injss);
  k_gemm<<<dim3(64, 8), 256, 0, stream>>>(nx, injT, injss, out);
}